// Round 9
// baseline (294.366 us; speedup 1.0000x reference)
//
#include <hip/hip_runtime.h>
#include <stdint.h>

// Self-attention, B=4, S=2048, D=1024, fp32 in/out, bf16 MFMA internally.
// R14: R11 (best, 221.2us; R12/R13 fusion reverted -- Mt straggler tail) with
//      ONE change: wave output tile 64x64 (acc 4x4) -> 128x64 (acc 8x4).
//      Mechanism: kernels are LDS-BW-bound (frag ds_reads 64KB + staging
//      writes 32KB per block-K-step x 4 blk/CU = ~530 GB/s demand vs ~300
//      capacity -- why MfmaUtil pinned at 37-39% across all variants).
//      8x4 acc amortizes A-frag reads over 2x rows: 96->80 KB per K-step.
//      Blocks become 2 waves (128 thr), same 128x128 tile, BK=64 XOR
//      swizzle unchanged, still 4 blocks/CU (launch_bounds(128,2), ~210 regs
//      <= 256 -> 2 waves/SIMD). Staging offsets: one base + p-strided
//      immediates (the (p*16)&7==0 identity makes the swizzle p-invariant).

typedef float f32x4 __attribute__((ext_vector_type(4)));
typedef short s16x8 __attribute__((ext_vector_type(8)));

__device__ __forceinline__ uint16_t f2bf(float f) {
    uint32_t u = __float_as_uint(f);
    u += 0x7fffu + ((u >> 16) & 1u);   // round-to-nearest-even
    return (uint16_t)(u >> 16);
}

#define GLOAD16(gp, lp)                                                  \
    __builtin_amdgcn_global_load_lds(                                    \
        (const __attribute__((address_space(1))) uint32_t*)(gp),         \
        (__attribute__((address_space(3))) uint32_t*)(lp), 16, 0, 0)

// bijective XCD-contiguity swizzle; valid because every grid here is %8==0.
__device__ __forceinline__ int xcd_swz(int b, int nwg) {
    return (b & 7) * (nwg >> 3) + (b >> 3);
}

// ---------------------------------------------------------------------------
// BK=64 swizzle (verified SQ_LDS_BANK_CONFLICT=0): LDS chunk cs (16B units)
// holds global kchunk (cs&7)^((cs>>3)&7) of row cs>>3. Fragment read for
// (row, kc): row*64 + (kc^(row&7))*8. C/D: row=(lane>>4)*4+reg, col=lane&15.
// 2-barrier K-loop, 128x128 tile, TWO waves (2x1 of 128x64), acc[8][4].
// With 128 threads: chunk cs = p*128 + t -> rr = p*16 + (t>>3) and the XOR
// term ((t&7)^((t>>3)&7)) is p-INVARIANT -> one offset reg + p*16-row strides.
// ---------------------------------------------------------------------------
__device__ __forceinline__ void gemm_core(
    uint16_t* __restrict__ As, uint16_t* __restrict__ Bs,
    const uint16_t* __restrict__ Ag, const int lda,
    const uint16_t* __restrict__ Bg, const int ldb,
    const int NT, f32x4 (&acc)[8][4])
{
    const int t = threadIdx.x;          // 0..127
    const int wave = t >> 6, lane = t & 63;
    const int wn = wave * 64;
    const int lr = lane & 15, hi = lane >> 4, lr7 = lane & 7;

    const int rr0 = t >> 3;                              // 0..15
    const int kc  = ((t & 7) ^ (rr0 & 7)) * 8;           // p-invariant
    uint32_t offA = (uint32_t)((rr0 * lda + kc) * 2);    // bytes
    uint32_t offB = (uint32_t)((rr0 * ldb + kc) * 2);
    const uint32_t stepA = (uint32_t)(32 * lda);         // 16 rows * 2B
    const uint32_t stepB = (uint32_t)(32 * ldb);
    const int lws = wave * 512;                          // u16 units

    for (int it = 0; it < NT; ++it) {
        uint32_t oA = offA, oB = offB;
#pragma unroll
        for (int p = 0; p < 16; ++p) {
            GLOAD16((const uint8_t*)Ag + oA, As + p * 1024 + lws);
            oA += stepA;
        }
#pragma unroll
        for (int p = 0; p < 16; ++p) {
            GLOAD16((const uint8_t*)Bg + oB, Bs + p * 1024 + lws);
            oB += stepB;
        }
        offA += 128; offB += 128;       // next BK=64 kchunk group
        __syncthreads();
#pragma unroll
        for (int kk = 0; kk < 2; ++kk) {
            const int lka = ((kk * 4 + hi) ^ lr7) * 8;
            s16x8 a[8], b[4];
#pragma unroll
            for (int i = 0; i < 8; ++i)
                a[i] = *(const s16x8*)(As + (i * 16 + lr) * 64 + lka);
#pragma unroll
            for (int j = 0; j < 4; ++j)
                b[j] = *(const s16x8*)(Bs + (wn + j * 16 + lr) * 64 + lka);
#pragma unroll
            for (int i = 0; i < 8; ++i)
#pragma unroll
                for (int j = 0; j < 4; ++j)
                    acc[i][j] = __builtin_amdgcn_mfma_f32_16x16x32_bf16(
                        a[i], b[j], acc[i][j], 0, 0, 0);
        }
        __syncthreads();
    }
}

// Projections, one dispatch, 1536 blocks x 128 thr (XCD-swizzled):
//   id < 1024: Q/K. mat=id>>9 (0=Q,1=K); rowblk=(id>>3)&63; colblk=id&7.
//              out = (x_tile @ W_tile^T + b) [*2^-5 for Q]
//   id >= 1024: V^T. vid=id-1024; rb=vid&7 (Vt rows); cb=vid>>3 (tokens).
//              Vt_tile = Wv_tile @ x_tile^T + bv(row)
__global__ __launch_bounds__(128, 2) void proj_all(
    const uint16_t* __restrict__ xb, const uint16_t* __restrict__ wqb,
    const uint16_t* __restrict__ wkb, const uint16_t* __restrict__ wvb,
    const float* __restrict__ bq, const float* __restrict__ bk,
    const float* __restrict__ bv,
    uint16_t* __restrict__ qb, uint16_t* __restrict__ kb,
    uint16_t* __restrict__ vtb)
{
    __shared__ __attribute__((aligned(16))) uint16_t As[128 * 64];
    __shared__ __attribute__((aligned(16))) uint16_t Bs[128 * 64];

    const int id = xcd_swz(blockIdx.x, 1536);
    const int t = threadIdx.x;
    const int wave = t >> 6, lane = t & 63;
    const int wn = wave * 64;
    const int lr = lane & 15, hi = lane >> 4;

    f32x4 acc[8][4] = {};

    if (id < 1024) {
        const int mat = id >> 9;
        const long long row0 = (long long)((id >> 3) & 63) * 128;
        const long long col0 = (long long)(id & 7) * 128;
        const uint16_t* W = mat ? wkb : wqb;
        gemm_core(As, Bs, xb + row0 * 1024, 1024, W + col0 * 1024, 1024, 16, acc);

        const float* bias = mat ? bk : bq;
        uint16_t* out = mat ? kb : qb;
        const float scale = mat ? 1.0f : 0.03125f;
#pragma unroll
        for (int i = 0; i < 8; ++i)
#pragma unroll
            for (int rr = 0; rr < 4; ++rr) {
                const long long row = row0 + i * 16 + hi * 4 + rr;
#pragma unroll
                for (int j = 0; j < 4; ++j) {
                    const long long col = col0 + wn + j * 16 + lr;
                    out[row * 1024 + col] = f2bf((acc[i][j][rr] + bias[col]) * scale);
                }
            }
    } else {
        const int vid = id - 1024;
        const long long row0 = (long long)(vid & 7) * 128;    // Vt row
        const long long col0 = (long long)(vid >> 3) * 128;   // token col
        gemm_core(As, Bs, wvb + row0 * 1024, 1024, xb + col0 * 1024, 1024, 16, acc);
#pragma unroll
        for (int i = 0; i < 8; ++i)
#pragma unroll
            for (int rr = 0; rr < 4; ++rr) {
                const long long row = row0 + i * 16 + hi * 4 + rr;
                const float bb = bv[row];
#pragma unroll
                for (int j = 0; j < 4; ++j) {
                    const long long col = col0 + wn + j * 16 + lr;
                    vtb[row * 8192 + col] = f2bf(acc[i][j][rr] + bb);
                }
            }
    }
}

// P = exp(Q @ K^T) + fused row-sum atomics. 1024 blocks x 128 thr.
__global__ __launch_bounds__(128, 2) void gemm_exp(
    const uint16_t* __restrict__ Q, const uint16_t* __restrict__ Km,
    uint16_t* __restrict__ P, float* __restrict__ sums)
{
    __shared__ __attribute__((aligned(16))) uint16_t As[128 * 64];
    __shared__ __attribute__((aligned(16))) uint16_t Bs[128 * 64];

    const int id = xcd_swz(blockIdx.x, 1024);
    const int z = id >> 8;
    const int rem = id & 255;
    const long long row0 = (long long)(rem & 15) * 128;
    const long long col0 = (long long)(rem >> 4) * 128;

    const uint16_t* Ab = Q  + (long long)z * 2048 * 1024 + row0 * 1024;
    const uint16_t* Bb = Km + (long long)z * 2048 * 1024 + col0 * 1024;
    uint16_t* Cb = P + (long long)z * 2048 * 2048;
    float* ax = sums + (long long)z * 2048;

    f32x4 acc[8][4] = {};
    gemm_core(As, Bs, Ab, 1024, Bb, 1024, 16, acc);

    const int t = threadIdx.x;
    const int wave = t >> 6, lane = t & 63;
    const int wn = wave * 64;
    const int lr = lane & 15, hi = lane >> 4;
#pragma unroll
    for (int i = 0; i < 8; ++i)
#pragma unroll
        for (int rr = 0; rr < 4; ++rr) {
            const long long row = row0 + i * 16 + hi * 4 + rr;
            float s = 0.f;
#pragma unroll
            for (int j = 0; j < 4; ++j) {
                const long long col = col0 + wn + j * 16 + lr;
                const float v = __expf(acc[i][j][rr]);
                Cb[row * 2048 + col] = f2bf(v);
                s += v;
            }
            s += __shfl_xor(s, 1);
            s += __shfl_xor(s, 2);
            s += __shfl_xor(s, 4);
            s += __shfl_xor(s, 8);
            if (lr == 0) atomicAdd(&ax[row], s);
        }
}

// out = (P @ V) * rcp(sums[row]). 512 blocks x 128 thr, NT=32.
__global__ __launch_bounds__(128, 2) void gemm_pv(
    const uint16_t* __restrict__ P, const uint16_t* __restrict__ Vt,
    float* __restrict__ Out, const float* __restrict__ sums)
{
    __shared__ __attribute__((aligned(16))) uint16_t As[128 * 64];
    __shared__ __attribute__((aligned(16))) uint16_t Bs[128 * 64];

    const int id = xcd_swz(blockIdx.x, 512);
    const int z = id >> 7;
    const int rem = id & 127;
    const long long row0 = (long long)(rem & 15) * 128;   // token row
    const long long col0 = (long long)(rem >> 4) * 128;   // D col

    const uint16_t* Ab = P + (long long)z * 2048 * 2048 + row0 * 2048;
    const uint16_t* Bb = Vt + col0 * 8192 + (long long)z * 2048;
    float* Cb = Out + (long long)z * 2048 * 1024;
    const float* ax = sums + (long long)z * 2048;

    f32x4 acc[8][4] = {};
    gemm_core(As, Bs, Ab, 2048, Bb, 8192, 32, acc);

    const int t = threadIdx.x;
    const int wave = t >> 6, lane = t & 63;
    const int wn = wave * 64;
    const int lr = lane & 15, hi = lane >> 4;
#pragma unroll
    for (int i = 0; i < 8; ++i)
#pragma unroll
        for (int rr = 0; rr < 4; ++rr) {
            const long long row = row0 + i * 16 + hi * 4 + rr;
            const float linv = __builtin_amdgcn_rcpf(ax[row]);
#pragma unroll
            for (int j = 0; j < 4; ++j) {
                const long long col = col0 + wn + j * 16 + lr;
                Cb[row * 1024 + col] = acc[i][j][rr] * linv;
            }
        }
}

// One dispatch: cast x (blocks 0..8191), Wq/Wk/Wv (8192..11263), zero sums.
__global__ void cast_all(const float* __restrict__ x, const float* __restrict__ Wq,
                         const float* __restrict__ Wk, const float* __restrict__ Wv,
                         uint16_t* __restrict__ xb, uint16_t* __restrict__ wqb,
                         uint16_t* __restrict__ wkb, uint16_t* __restrict__ wvb,
                         float* __restrict__ sums) {
    const int b = blockIdx.x;
    const float* in;
    uint16_t* out;
    int i;
    if (b < 8192)       { in = x;  out = xb;  i = b * 256 + threadIdx.x; }
    else if (b < 9216)  { in = Wq; out = wqb; i = (b - 8192) * 256 + threadIdx.x; }
    else if (b < 10240) { in = Wk; out = wkb; i = (b - 9216) * 256 + threadIdx.x; }
    else if (b < 11264) { in = Wv; out = wvb; i = (b - 10240) * 256 + threadIdx.x; }
    else {
        int j = (b - 11264) * 256 + threadIdx.x;   // 8 blocks x 256 x float4 = 8192
        ((float4*)sums)[j] = make_float4(0.f, 0.f, 0.f, 0.f);
        return;
    }
    float4 v = ((const float4*)in)[i];
    ushort4 o = make_ushort4(f2bf(v.x), f2bf(v.y), f2bf(v.z), f2bf(v.w));
    ((ushort4*)out)[i] = o;
}

extern "C" void kernel_launch(void* const* d_in, const int* in_sizes, int n_in,
                              void* d_out, int out_size, void* d_ws, size_t ws_size,
                              hipStream_t stream) {
    const float* x  = (const float*)d_in[0];
    const float* Wq = (const float*)d_in[1];
    const float* bq = (const float*)d_in[2];
    const float* Wk = (const float*)d_in[3];
    const float* bk = (const float*)d_in[4];
    const float* Wv = (const float*)d_in[5];
    const float* bv = (const float*)d_in[6];

    // workspace carve (~102 MiB)
    uint8_t* w = (uint8_t*)d_ws;
    uint16_t* xb  = (uint16_t*)w; w += (size_t)8192 * 1024 * 2;
    uint16_t* wqb = (uint16_t*)w; w += (size_t)1024 * 1024 * 2;
    uint16_t* wkb = (uint16_t*)w; w += (size_t)1024 * 1024 * 2;
    uint16_t* wvb = (uint16_t*)w; w += (size_t)1024 * 1024 * 2;
    uint16_t* qb  = (uint16_t*)w; w += (size_t)8192 * 1024 * 2;
    uint16_t* kb  = (uint16_t*)w; w += (size_t)8192 * 1024 * 2;
    uint16_t* vtb = (uint16_t*)w; w += (size_t)8192 * 1024 * 2;   // [1024][8192]
    uint16_t* pb  = (uint16_t*)w; w += (size_t)4 * 2048 * 2048 * 2;
    float*    sums = (float*)w;  w += (size_t)8192 * 4;

    // casts + zero the exp-sum accumulator (1 dispatch)
    cast_all<<<dim3(11272), dim3(256), 0, stream>>>(x, Wq, Wk, Wv,
                                                    xb, wqb, wkb, wvb, sums);
    // Q (pre-scaled 2^-5), K, V^T: 128x128 tiles, 2-wave blocks, 4/CU
    proj_all<<<dim3(1536), dim3(128), 0, stream>>>(xb, wqb, wkb, wvb,
                                                   bq, bk, bv, qb, kb, vtb);
    // P = exp(Q @ K^T) + fused row sums: 1024 blocks
    gemm_exp<<<dim3(1024), dim3(128), 0, stream>>>(qb, kb, pb, sums);
    // out = (P @ V) * rcp(sums): 512 blocks
    gemm_pv<<<dim3(512), dim3(128), 0, stream>>>(pb, vtb, (float*)d_out, sums);
}